// Round 3
// baseline (372.118 us; speedup 1.0000x reference)
//
#include <hip/hip_runtime.h>
#include <math.h>

#define N_NODES   150000
#define N_EDGES   1500000
#define N_GRAPHS  150
#define HID       100
#define BATCH     30
#define SEQ       5
#define NODES_PER_GRAPH 1000
#define NREP      8

// ---------------- zero the accumulator region ----------------
__global__ void k_zero4(float4* p, int n4) {
    int i = blockIdx.x * blockDim.x + threadIdx.x;
    int stride = gridDim.x * blockDim.x;
    for (; i < n4; i += stride) p[i] = make_float4(0.f, 0.f, 0.f, 0.f);
}

// ---------------- degree count into 8 replicas ----------------
__global__ void k_deg_count(const int* __restrict__ dst, float* __restrict__ degR) {
    int e = blockIdx.x * blockDim.x + threadIdx.x;
    if (e < N_EDGES) {
        int r = blockIdx.x & (NREP - 1);
        atomicAdd(&degR[r * N_NODES + dst[e]], 1.0f);
    }
}

// deg = 1 + sum(replicas); p[i] = (dinv, dinv*x)
__global__ void k_node_init(const float* __restrict__ degR, const float* __restrict__ x,
                            float2* __restrict__ p) {
    int i = blockIdx.x * blockDim.x + threadIdx.x;
    if (i < N_NODES) {
        float s = 1.0f;
        #pragma unroll
        for (int r = 0; r < NREP; ++r) s += degR[r * N_NODES + i];
        float dv = 1.0f / sqrtf(s);
        p[i] = make_float2(dv, dv * x[i]);
    }
}

// edge pass 1: tR[r][d] += (dinv[s], dinv[s]*x[s])
__global__ void k_edge1(const int* __restrict__ src, const int* __restrict__ dst,
                        const float2* __restrict__ p, float2* __restrict__ tR) {
    int e = blockIdx.x * blockDim.x + threadIdx.x;
    if (e < N_EDGES) {
        int r = blockIdx.x & (NREP - 1);
        int s = src[e], d = dst[e];
        float2 pv = p[s];
        float2* tp = &tR[r * N_NODES + d];
        atomicAdd(&tp->x, pv.x);
        atomicAdd(&tp->y, pv.y);
    }
}

// agg1 = dinv*(t1 + dinv*x); wsum = dinv*(t2 + dinv); a1s = dinv*agg1
__global__ void k_finalize1(const float2* __restrict__ tR, const float2* __restrict__ p,
                            float* __restrict__ agg1, float* __restrict__ wsum,
                            float* __restrict__ a1s) {
    int i = blockIdx.x * blockDim.x + threadIdx.x;
    if (i < N_NODES) {
        float t2 = 0.f, t1 = 0.f;
        #pragma unroll
        for (int r = 0; r < NREP; ++r) {
            float2 tv = tR[r * N_NODES + i];
            t2 += tv.x; t1 += tv.y;
        }
        float2 pv = p[i];
        float dv = pv.x;
        float a = dv * t1 + dv * pv.y;     // dinv*(t1 + dinv*x)
        agg1[i] = a;
        wsum[i] = dv * (t2 + dv);
        a1s[i]  = dv * a;
    }
}

// edge pass 2: uR[r][d] += a1s[s]
__global__ void k_edge2(const int* __restrict__ src, const int* __restrict__ dst,
                        const float* __restrict__ a1s, float* __restrict__ uR) {
    int e = blockIdx.x * blockDim.x + threadIdx.x;
    if (e < N_EDGES) {
        int r = blockIdx.x & (NREP - 1);
        atomicAdd(&uR[r * N_NODES + dst[e]], a1s[src[e]]);
    }
}

// agg2 = dinv*(sum(uR) + dinv*agg1)
__global__ void k_finalize2(const float* __restrict__ uR, const float2* __restrict__ p,
                            const float* __restrict__ agg1, float* __restrict__ agg2) {
    int i = blockIdx.x * blockDim.x + threadIdx.x;
    if (i < N_NODES) {
        float u = 0.f;
        #pragma unroll
        for (int r = 0; r < NREP; ++r) u += uR[r * N_NODES + i];
        float dv = p[i].x;
        agg2[i] = dv * (u + dv * agg1[i]);
    }
}

// ---------------- fused tail: v1/v2, per-graph means, LSTM, head -----------
__global__ __launch_bounds__(512) void k_tail(const float* __restrict__ agg2,
                                              const float* __restrict__ wsum,
                                              const float* __restrict__ W1,
                                              const float* __restrict__ b1,
                                              const float* __restrict__ W2,
                                              const float* __restrict__ b2,
                                              const float* __restrict__ W_ih,
                                              const float* __restrict__ W_hh,
                                              const float* __restrict__ b_ih,
                                              const float* __restrict__ b_hh,
                                              const float* __restrict__ W_out,
                                              const float* __restrict__ b_out,
                                              float* __restrict__ outp) {
    int b = blockIdx.x;
    int t = threadIdx.x;
    __shared__ float v1[HID], v2[HID];
    __shared__ float hs[HID], cs[HID], xs[HID], gs[4 * HID];
    __shared__ float red_a[512], red_w[512];
    __shared__ float mean_a_s, mean_w_s;

    if (t < HID) {
        float a = 0.0f, c = 0.0f;
        for (int k = 0; k < HID; ++k) {
            float w2 = W2[k * HID + t];
            a += W1[k] * w2;
            c += b1[k] * w2;
        }
        v1[t] = a; v2[t] = c;
        hs[t] = 0.0f; cs[t] = 0.0f;
    }
    __syncthreads();

    for (int step = 0; step < SEQ; ++step) {
        int g = b * SEQ + step;
        const float* pa = agg2 + (size_t)g * NODES_PER_GRAPH;
        const float* pw = wsum + (size_t)g * NODES_PER_GRAPH;
        float sa = 0.0f, sw = 0.0f;
        for (int n = t; n < NODES_PER_GRAPH; n += 512) { sa += pa[n]; sw += pw[n]; }
        red_a[t] = sa; red_w[t] = sw;
        __syncthreads();
        for (int s = 256; s > 0; s >>= 1) {
            if (t < s) { red_a[t] += red_a[t + s]; red_w[t] += red_w[t + s]; }
            __syncthreads();
        }
        if (t == 0) {
            mean_a_s = red_a[0] * (1.0f / NODES_PER_GRAPH);
            mean_w_s = red_w[0] * (1.0f / NODES_PER_GRAPH);
        }
        __syncthreads();
        if (t < HID) xs[t] = mean_a_s * v1[t] + mean_w_s * v2[t] + b2[t];
        __syncthreads();
        if (t < 4 * HID) {
            float acc = b_ih[t] + b_hh[t];
            const float* wi = W_ih + t * HID;
            const float* wh = W_hh + t * HID;
            for (int k = 0; k < HID; ++k)
                acc += xs[k] * wi[k] + hs[k] * wh[k];
            gs[t] = acc;
        }
        __syncthreads();
        if (t < HID) {
            float ig = 1.0f / (1.0f + expf(-gs[t]));
            float fg = 1.0f / (1.0f + expf(-gs[HID + t]));
            float gg = tanhf(gs[2 * HID + t]);
            float og = 1.0f / (1.0f + expf(-gs[3 * HID + t]));
            float c  = fg * cs[t] + ig * gg;
            cs[t] = c;
            hs[t] = og * tanhf(c);
        }
        __syncthreads();
    }

    float v = (t < HID) ? hs[t] * W_out[t] : 0.0f;
    red_a[t] = v;
    __syncthreads();
    for (int s = 256; s > 0; s >>= 1) {
        if (t < s) red_a[t] += red_a[t + s];
        __syncthreads();
    }
    if (t == 0) outp[b] = red_a[0] + b_out[0];
}

// ---------------- launch ----------------
extern "C" void kernel_launch(void* const* d_in, const int* in_sizes, int n_in,
                              void* d_out, int out_size, void* d_ws, size_t ws_size,
                              hipStream_t stream) {
    const float* x    = (const float*)d_in[0];
    const int*   ei   = (const int*)d_in[1];
    const int*   srcp = ei;
    const int*   dstp = ei + N_EDGES;
    const float* W1   = (const float*)d_in[3];
    const float* b1   = (const float*)d_in[4];
    const float* W2   = (const float*)d_in[5];
    const float* b2   = (const float*)d_in[6];
    const float* W_ih = (const float*)d_in[7];
    const float* W_hh = (const float*)d_in[8];
    const float* b_ih = (const float*)d_in[9];
    const float* b_hh = (const float*)d_in[10];
    const float* W_out= (const float*)d_in[11];
    const float* b_out= (const float*)d_in[12];
    float* out = (float*)d_out;

    // workspace layout (floats). Zeroed region first: degR(8N) tR(16N) uR(8N)
    float*  ws   = (float*)d_ws;
    float*  degR = ws;                              // 8N
    float2* tR   = (float2*)(ws + 8 * N_NODES);     // 8N float2 = 16N floats
    float*  uR   = ws + 24 * N_NODES;               // 8N
    float2* p    = (float2*)(ws + 32 * N_NODES);    // N float2 = 2N floats
    float*  agg1 = ws + 34 * N_NODES;               // N
    float*  wsum = ws + 35 * N_NODES;               // N
    float*  a1s  = ws + 36 * N_NODES;               // N
    float*  agg2 = ws + 37 * N_NODES;               // N

    const int B = 256;
    int gN = (N_NODES + B - 1) / B;
    int gE = (N_EDGES + B - 1) / B;

    k_zero4<<<2048, B, 0, stream>>>((float4*)ws, 32 * N_NODES / 4);
    k_deg_count<<<gE, B, 0, stream>>>(dstp, degR);
    k_node_init<<<gN, B, 0, stream>>>(degR, x, p);
    k_edge1<<<gE, B, 0, stream>>>(srcp, dstp, p, tR);
    k_finalize1<<<gN, B, 0, stream>>>(tR, p, agg1, wsum, a1s);
    k_edge2<<<gE, B, 0, stream>>>(srcp, dstp, a1s, uR);
    k_finalize2<<<gN, B, 0, stream>>>(uR, p, agg1, agg2);
    k_tail<<<BATCH, 512, 0, stream>>>(agg2, wsum, W1, b1, W2, b2,
                                      W_ih, W_hh, b_ih, b_hh, W_out, b_out, out);
}

// Round 4
// 131.055 us; speedup vs baseline: 2.8394x; 2.8394x over previous
//
#include <hip/hip_runtime.h>
#include <math.h>

#define N_NODES   150000
#define N_EDGES   1500000
#define N_GRAPHS  150
#define HID       100
#define BATCH     30
#define SEQ       5
#define NODES_PER_GRAPH 1000

#define NPB       256                       // nodes per bucket
#define NB        ((N_NODES + NPB - 1) / NPB)   // 586 buckets
#define SBLK      128                       // blocks for hist/scatter passes
#define EPB       11720                     // edges per sort block (mult of 4, 128*11720 >= E)

// ---------------- zero bucket counters ----------------
__global__ void k_zero(int* p, int n) {
    int i = blockIdx.x * blockDim.x + threadIdx.x;
    for (; i < n; i += blockDim.x * gridDim.x) p[i] = 0;
}

// ---------------- S1: per-block histogram + global reservation -------------
__global__ __launch_bounds__(256) void k_s1(const int* __restrict__ dst,
                                            int* __restrict__ bucketCount,
                                            int* __restrict__ blockBase) {
    __shared__ int hist[NB];
    int t = threadIdx.x;
    for (int i = t; i < NB; i += 256) hist[i] = 0;
    __syncthreads();
    int base = blockIdx.x * EPB;
    int end  = min(base + EPB, N_EDGES);
    for (int i = base + t * 4; i < end; i += 1024) {
        int4 d = *reinterpret_cast<const int4*>(dst + i);
        atomicAdd(&hist[d.x >> 8], 1);
        atomicAdd(&hist[d.y >> 8], 1);
        atomicAdd(&hist[d.z >> 8], 1);
        atomicAdd(&hist[d.w >> 8], 1);
    }
    __syncthreads();
    for (int b = t; b < NB; b += 256) {
        int c = hist[b];
        blockBase[blockIdx.x * NB + b] = (c > 0) ? atomicAdd(&bucketCount[b], c) : 0;
    }
}

// ---------------- scan: exclusive prefix over bucketCount ------------------
__global__ __launch_bounds__(256) void k_scan(const int* __restrict__ cnt,
                                              int* __restrict__ start) {
    __shared__ int part[256];
    int t = threadIdx.x;
    int j0 = t * 3;
    int s = 0;
    #pragma unroll
    for (int k = 0; k < 3; ++k) { int j = j0 + k; if (j < NB) s += cnt[j]; }
    part[t] = s;
    __syncthreads();
    for (int off = 1; off < 256; off <<= 1) {
        int w = (t >= off) ? part[t - off] : 0;
        __syncthreads();
        part[t] += w;
        __syncthreads();
    }
    int run = part[t] - s;   // exclusive prefix of this thread's chunk
    #pragma unroll
    for (int k = 0; k < 3; ++k) {
        int j = j0 + k;
        if (j < NB) { start[j] = run; run += cnt[j]; }
    }
    if (t == 0) start[NB] = N_EDGES;
}

// ---------------- S2: scatter packed (src<<8 | dlocal) by bucket -----------
__global__ __launch_bounds__(256) void k_s2(const int* __restrict__ src,
                                            const int* __restrict__ dst,
                                            const int* __restrict__ bucketStart,
                                            const int* __restrict__ blockBase,
                                            unsigned int* __restrict__ sorted) {
    __shared__ int cursor[NB];
    int t = threadIdx.x;
    for (int i = t; i < NB; i += 256) cursor[i] = 0;
    __syncthreads();
    int base = blockIdx.x * EPB;
    int end  = min(base + EPB, N_EDGES);
    const int* bb = blockBase + blockIdx.x * NB;
    for (int i = base + t * 4; i < end; i += 1024) {
        int4 s4 = *reinterpret_cast<const int4*>(src + i);
        int4 d4 = *reinterpret_cast<const int4*>(dst + i);
        int bs[4] = { d4.x >> 8, d4.y >> 8, d4.z >> 8, d4.w >> 8 };
        int sv[4] = { s4.x, s4.y, s4.z, s4.w };
        int dl[4] = { d4.x & 255, d4.y & 255, d4.z & 255, d4.w & 255 };
        #pragma unroll
        for (int k = 0; k < 4; ++k) {
            int b = bs[k];
            int idx = atomicAdd(&cursor[b], 1);
            int pos = bucketStart[b] + bb[b] + idx;
            sorted[pos] = ((unsigned int)sv[k] << 8) | (unsigned int)dl[k];
        }
    }
}

// ---------------- accumA: degree -> dinv, p = (dinv, dinv*x) ---------------
__global__ __launch_bounds__(256) void k_accA(const unsigned int* __restrict__ sorted,
                                              const int* __restrict__ bucketStart,
                                              const float* __restrict__ x,
                                              float2* __restrict__ p) {
    __shared__ int degI[NPB];
    int b = blockIdx.x;
    int t = threadIdx.x;
    int n0 = b << 8;
    int nn = min(NPB, N_NODES - n0);
    degI[t] = 0;
    __syncthreads();
    int e0 = bucketStart[b], e1 = bucketStart[b + 1];
    for (int i = e0 + t; i < e1; i += 256)
        atomicAdd(&degI[sorted[i] & 255], 1);
    __syncthreads();
    if (t < nn) {
        float dv = 1.0f / sqrtf((float)(1 + degI[t]));
        p[n0 + t] = make_float2(dv, dv * x[n0 + t]);
    }
}

// ---------------- accumB: t1,t2 -> agg1, wsum, a1s -------------------------
__global__ __launch_bounds__(256) void k_accB(const unsigned int* __restrict__ sorted,
                                              const int* __restrict__ bucketStart,
                                              const float2* __restrict__ p,
                                              float* __restrict__ agg1,
                                              float* __restrict__ wsum,
                                              float* __restrict__ a1s) {
    __shared__ float t1[NPB], t2[NPB];
    int b = blockIdx.x;
    int t = threadIdx.x;
    int n0 = b << 8;
    int nn = min(NPB, N_NODES - n0);
    t1[t] = 0.0f; t2[t] = 0.0f;
    __syncthreads();
    int e0 = bucketStart[b], e1 = bucketStart[b + 1];
    for (int i = e0 + t; i < e1; i += 256) {
        unsigned int u = sorted[i];
        float2 pv = p[u >> 8];
        int dl = u & 255;
        atomicAdd(&t2[dl], pv.x);
        atomicAdd(&t1[dl], pv.y);
    }
    __syncthreads();
    if (t < nn) {
        float2 pv = p[n0 + t];
        float dv = pv.x;
        float a = dv * t1[t] + dv * pv.y;   // dinv*(t1 + dinv*x)
        agg1[n0 + t] = a;
        wsum[n0 + t] = dv * (t2[t] + dv);
        a1s[n0 + t]  = dv * a;
    }
}

// ---------------- accumC: u -> agg2 ----------------------------------------
__global__ __launch_bounds__(256) void k_accC(const unsigned int* __restrict__ sorted,
                                              const int* __restrict__ bucketStart,
                                              const float2* __restrict__ p,
                                              const float* __restrict__ agg1,
                                              const float* __restrict__ a1s,
                                              float* __restrict__ agg2) {
    __shared__ float ua[NPB];
    int b = blockIdx.x;
    int t = threadIdx.x;
    int n0 = b << 8;
    int nn = min(NPB, N_NODES - n0);
    ua[t] = 0.0f;
    __syncthreads();
    int e0 = bucketStart[b], e1 = bucketStart[b + 1];
    for (int i = e0 + t; i < e1; i += 256) {
        unsigned int u = sorted[i];
        atomicAdd(&ua[u & 255], a1s[u >> 8]);
    }
    __syncthreads();
    if (t < nn) {
        float dv = p[n0 + t].x;
        agg2[n0 + t] = dv * (ua[t] + dv * agg1[n0 + t]);
    }
}

// ---------------- fused tail: v1/v2, per-graph means, LSTM, head -----------
__global__ __launch_bounds__(512) void k_tail(const float* __restrict__ agg2,
                                              const float* __restrict__ wsum,
                                              const float* __restrict__ W1,
                                              const float* __restrict__ b1,
                                              const float* __restrict__ W2,
                                              const float* __restrict__ b2,
                                              const float* __restrict__ W_ih,
                                              const float* __restrict__ W_hh,
                                              const float* __restrict__ b_ih,
                                              const float* __restrict__ b_hh,
                                              const float* __restrict__ W_out,
                                              const float* __restrict__ b_out,
                                              float* __restrict__ outp) {
    int b = blockIdx.x;
    int t = threadIdx.x;
    __shared__ float v1[HID], v2[HID];
    __shared__ float hs[HID], cs[HID], xs[HID], gs[4 * HID];
    __shared__ float red_a[512], red_w[512];
    __shared__ float mean_a_s, mean_w_s;

    if (t < HID) {
        float a = 0.0f, c = 0.0f;
        for (int k = 0; k < HID; ++k) {
            float w2 = W2[k * HID + t];
            a += W1[k] * w2;
            c += b1[k] * w2;
        }
        v1[t] = a; v2[t] = c;
        hs[t] = 0.0f; cs[t] = 0.0f;
    }
    __syncthreads();

    for (int step = 0; step < SEQ; ++step) {
        int g = b * SEQ + step;
        const float* pa = agg2 + (size_t)g * NODES_PER_GRAPH;
        const float* pw = wsum + (size_t)g * NODES_PER_GRAPH;
        float sa = 0.0f, sw = 0.0f;
        for (int n = t; n < NODES_PER_GRAPH; n += 512) { sa += pa[n]; sw += pw[n]; }
        red_a[t] = sa; red_w[t] = sw;
        __syncthreads();
        for (int s = 256; s > 0; s >>= 1) {
            if (t < s) { red_a[t] += red_a[t + s]; red_w[t] += red_w[t + s]; }
            __syncthreads();
        }
        if (t == 0) {
            mean_a_s = red_a[0] * (1.0f / NODES_PER_GRAPH);
            mean_w_s = red_w[0] * (1.0f / NODES_PER_GRAPH);
        }
        __syncthreads();
        if (t < HID) xs[t] = mean_a_s * v1[t] + mean_w_s * v2[t] + b2[t];
        __syncthreads();
        if (t < 4 * HID) {
            float acc = b_ih[t] + b_hh[t];
            const float* wi = W_ih + t * HID;
            const float* wh = W_hh + t * HID;
            for (int k = 0; k < HID; ++k)
                acc += xs[k] * wi[k] + hs[k] * wh[k];
            gs[t] = acc;
        }
        __syncthreads();
        if (t < HID) {
            float ig = 1.0f / (1.0f + expf(-gs[t]));
            float fg = 1.0f / (1.0f + expf(-gs[HID + t]));
            float gg = tanhf(gs[2 * HID + t]);
            float og = 1.0f / (1.0f + expf(-gs[3 * HID + t]));
            float c  = fg * cs[t] + ig * gg;
            cs[t] = c;
            hs[t] = og * tanhf(c);
        }
        __syncthreads();
    }

    float v = (t < HID) ? hs[t] * W_out[t] : 0.0f;
    red_a[t] = v;
    __syncthreads();
    for (int s = 256; s > 0; s >>= 1) {
        if (t < s) red_a[t] += red_a[t + s];
        __syncthreads();
    }
    if (t == 0) outp[b] = red_a[0] + b_out[0];
}

// ---------------- launch ----------------
extern "C" void kernel_launch(void* const* d_in, const int* in_sizes, int n_in,
                              void* d_out, int out_size, void* d_ws, size_t ws_size,
                              hipStream_t stream) {
    const float* x    = (const float*)d_in[0];
    const int*   ei   = (const int*)d_in[1];
    const int*   srcp = ei;
    const int*   dstp = ei + N_EDGES;
    const float* W1   = (const float*)d_in[3];
    const float* b1   = (const float*)d_in[4];
    const float* W2   = (const float*)d_in[5];
    const float* b2   = (const float*)d_in[6];
    const float* W_ih = (const float*)d_in[7];
    const float* W_hh = (const float*)d_in[8];
    const float* b_ih = (const float*)d_in[9];
    const float* b_hh = (const float*)d_in[10];
    const float* W_out= (const float*)d_in[11];
    const float* b_out= (const float*)d_in[12];
    float* out = (float*)d_out;

    // workspace layout
    char* w = (char*)d_ws;
    int*  bucketCount = (int*)w;                         w += NB * sizeof(int);
    int*  bucketStart = (int*)w;                         w += (NB + 1) * sizeof(int);
    int*  blockBase   = (int*)w;                         w += (size_t)SBLK * NB * sizeof(int);
    unsigned int* sorted = (unsigned int*)w;             w += (size_t)N_EDGES * sizeof(unsigned int);
    float2* p   = (float2*)w;                            w += (size_t)N_NODES * sizeof(float2);
    float* agg1 = (float*)w;                             w += (size_t)N_NODES * sizeof(float);
    float* wsum = (float*)w;                             w += (size_t)N_NODES * sizeof(float);
    float* a1s  = (float*)w;                             w += (size_t)N_NODES * sizeof(float);
    float* agg2 = (float*)w;                             w += (size_t)N_NODES * sizeof(float);

    k_zero<<<2, 256, 0, stream>>>(bucketCount, NB);
    k_s1  <<<SBLK, 256, 0, stream>>>(dstp, bucketCount, blockBase);
    k_scan<<<1, 256, 0, stream>>>(bucketCount, bucketStart);
    k_s2  <<<SBLK, 256, 0, stream>>>(srcp, dstp, bucketStart, blockBase, sorted);
    k_accA<<<NB, 256, 0, stream>>>(sorted, bucketStart, x, p);
    k_accB<<<NB, 256, 0, stream>>>(sorted, bucketStart, p, agg1, wsum, a1s);
    k_accC<<<NB, 256, 0, stream>>>(sorted, bucketStart, p, agg1, a1s, agg2);
    k_tail<<<BATCH, 512, 0, stream>>>(agg2, wsum, W1, b1, W2, b2,
                                      W_ih, W_hh, b_ih, b_hh, W_out, b_out, out);
}

// Round 5
// 99.691 us; speedup vs baseline: 3.7327x; 1.3146x over previous
//
#include <hip/hip_runtime.h>
#include <math.h>

#define N_NODES   150000
#define N_EDGES   1500000
#define N_GRAPHS  150
#define HID       100
#define BATCH     30
#define SEQ       5
#define NODES_PER_GRAPH 1000

#define NPB       256                       // nodes per bucket
#define NB        ((N_NODES + NPB - 1) / NPB)   // 586 buckets
#define SBLK      128                       // blocks for hist/scatter passes
#define EPB       11720                     // edges per sort block (mult of 4, 128*11720 >= E)

// ---------------- zero bucket counters ----------------
__global__ void k_zero(int* p, int n) {
    int i = blockIdx.x * blockDim.x + threadIdx.x;
    for (; i < n; i += blockDim.x * gridDim.x) p[i] = 0;
}

// ---------------- S1: per-block histogram + global reservation -------------
__global__ __launch_bounds__(256) void k_s1(const int* __restrict__ dst,
                                            int* __restrict__ bucketCount,
                                            int* __restrict__ blockBase) {
    __shared__ int hist[NB];
    int t = threadIdx.x;
    for (int i = t; i < NB; i += 256) hist[i] = 0;
    __syncthreads();
    int base = blockIdx.x * EPB;
    int end  = min(base + EPB, N_EDGES);
    for (int i = base + t * 4; i < end; i += 1024) {
        int4 d = *reinterpret_cast<const int4*>(dst + i);
        atomicAdd(&hist[d.x >> 8], 1);
        atomicAdd(&hist[d.y >> 8], 1);
        atomicAdd(&hist[d.z >> 8], 1);
        atomicAdd(&hist[d.w >> 8], 1);
    }
    __syncthreads();
    for (int b = t; b < NB; b += 256) {
        int c = hist[b];
        blockBase[blockIdx.x * NB + b] = (c > 0) ? atomicAdd(&bucketCount[b], c) : 0;
    }
}

// ---------------- scan: exclusive prefix over bucketCount ------------------
__global__ __launch_bounds__(256) void k_scan(const int* __restrict__ cnt,
                                              int* __restrict__ start) {
    __shared__ int part[256];
    int t = threadIdx.x;
    int j0 = t * 3;
    int s = 0;
    #pragma unroll
    for (int k = 0; k < 3; ++k) { int j = j0 + k; if (j < NB) s += cnt[j]; }
    part[t] = s;
    __syncthreads();
    for (int off = 1; off < 256; off <<= 1) {
        int w = (t >= off) ? part[t - off] : 0;
        __syncthreads();
        part[t] += w;
        __syncthreads();
    }
    int run = part[t] - s;   // exclusive prefix of this thread's chunk
    #pragma unroll
    for (int k = 0; k < 3; ++k) {
        int j = j0 + k;
        if (j < NB) { start[j] = run; run += cnt[j]; }
    }
    if (t == 0) start[NB] = N_EDGES;
}

// ---------------- S2: scatter packed (src<<8 | dlocal) by bucket -----------
__global__ __launch_bounds__(256) void k_s2(const int* __restrict__ src,
                                            const int* __restrict__ dst,
                                            const int* __restrict__ bucketStart,
                                            const int* __restrict__ blockBase,
                                            unsigned int* __restrict__ sorted) {
    __shared__ int cursor[NB];
    int t = threadIdx.x;
    for (int i = t; i < NB; i += 256) cursor[i] = 0;
    __syncthreads();
    int base = blockIdx.x * EPB;
    int end  = min(base + EPB, N_EDGES);
    const int* bb = blockBase + blockIdx.x * NB;
    for (int i = base + t * 4; i < end; i += 1024) {
        int4 s4 = *reinterpret_cast<const int4*>(src + i);
        int4 d4 = *reinterpret_cast<const int4*>(dst + i);
        int bs[4] = { d4.x >> 8, d4.y >> 8, d4.z >> 8, d4.w >> 8 };
        int sv[4] = { s4.x, s4.y, s4.z, s4.w };
        int dl[4] = { d4.x & 255, d4.y & 255, d4.z & 255, d4.w & 255 };
        #pragma unroll
        for (int k = 0; k < 4; ++k) {
            int b = bs[k];
            int idx = atomicAdd(&cursor[b], 1);
            int pos = bucketStart[b] + bb[b] + idx;
            sorted[pos] = ((unsigned int)sv[k] << 8) | (unsigned int)dl[k];
        }
    }
}

// ---------------- accumA: degree -> dinv, p = (dinv, dinv*x) ---------------
__global__ __launch_bounds__(256) void k_accA(const unsigned int* __restrict__ sorted,
                                              const int* __restrict__ bucketStart,
                                              const float* __restrict__ x,
                                              float2* __restrict__ p) {
    __shared__ int degI[NPB];
    int b = blockIdx.x;
    int t = threadIdx.x;
    int n0 = b << 8;
    int nn = min(NPB, N_NODES - n0);
    degI[t] = 0;
    __syncthreads();
    int e0 = bucketStart[b], e1 = bucketStart[b + 1];
    for (int i = e0 + t; i < e1; i += 256)
        atomicAdd(&degI[sorted[i] & 255], 1);
    __syncthreads();
    if (t < nn) {
        float dv = 1.0f / sqrtf((float)(1 + degI[t]));
        p[n0 + t] = make_float2(dv, dv * x[n0 + t]);
    }
}

// ---------------- accumB: t1,t2 -> agg1, wsum, a1s -------------------------
__global__ __launch_bounds__(256) void k_accB(const unsigned int* __restrict__ sorted,
                                              const int* __restrict__ bucketStart,
                                              const float2* __restrict__ p,
                                              float* __restrict__ agg1,
                                              float* __restrict__ wsum,
                                              float* __restrict__ a1s) {
    __shared__ float t1[NPB], t2[NPB];
    int b = blockIdx.x;
    int t = threadIdx.x;
    int n0 = b << 8;
    int nn = min(NPB, N_NODES - n0);
    t1[t] = 0.0f; t2[t] = 0.0f;
    __syncthreads();
    int e0 = bucketStart[b], e1 = bucketStart[b + 1];
    for (int i = e0 + t; i < e1; i += 256) {
        unsigned int u = sorted[i];
        float2 pv = p[u >> 8];
        int dl = u & 255;
        atomicAdd(&t2[dl], pv.x);
        atomicAdd(&t1[dl], pv.y);
    }
    __syncthreads();
    if (t < nn) {
        float2 pv = p[n0 + t];
        float dv = pv.x;
        float a = dv * t1[t] + dv * pv.y;   // dinv*(t1 + dinv*x)
        agg1[n0 + t] = a;
        wsum[n0 + t] = dv * (t2[t] + dv);
        a1s[n0 + t]  = dv * a;
    }
}

// ---------------- accumC: u -> agg2 ----------------------------------------
__global__ __launch_bounds__(256) void k_accC(const unsigned int* __restrict__ sorted,
                                              const int* __restrict__ bucketStart,
                                              const float2* __restrict__ p,
                                              const float* __restrict__ agg1,
                                              const float* __restrict__ a1s,
                                              float* __restrict__ agg2) {
    __shared__ float ua[NPB];
    int b = blockIdx.x;
    int t = threadIdx.x;
    int n0 = b << 8;
    int nn = min(NPB, N_NODES - n0);
    ua[t] = 0.0f;
    __syncthreads();
    int e0 = bucketStart[b], e1 = bucketStart[b + 1];
    for (int i = e0 + t; i < e1; i += 256) {
        unsigned int u = sorted[i];
        atomicAdd(&ua[u & 255], a1s[u >> 8]);
    }
    __syncthreads();
    if (t < nn) {
        float dv = p[n0 + t].x;
        agg2[n0 + t] = dv * (ua[t] + dv * agg1[n0 + t]);
    }
}

// ---------------- pre: per-graph means -> xs -> Xg (input gates) -----------
// Xg[g][t] = b_ih[t] + b_hh[t] + sum_k xs[g][k] * W_ih[t][k]
// xs[g][k] = mean_a[g]*v1[k] + mean_w[g]*v2[k] + b2[k]
__global__ __launch_bounds__(512) void k_pre(const float* __restrict__ agg2,
                                             const float* __restrict__ wsum,
                                             const float* __restrict__ W1,
                                             const float* __restrict__ b1,
                                             const float* __restrict__ W2,
                                             const float* __restrict__ b2,
                                             const float* __restrict__ W_ih,
                                             const float* __restrict__ b_ih,
                                             const float* __restrict__ b_hh,
                                             float* __restrict__ Xg) {
    int g = blockIdx.x;            // 0..149
    int t = threadIdx.x;
    __shared__ float xs[HID];
    __shared__ float red_a[512], red_w[512];

    // per-graph means
    const float* pa = agg2 + (size_t)g * NODES_PER_GRAPH;
    const float* pw = wsum + (size_t)g * NODES_PER_GRAPH;
    float sa = 0.0f, sw = 0.0f;
    for (int n = t; n < NODES_PER_GRAPH; n += 512) { sa += pa[n]; sw += pw[n]; }
    red_a[t] = sa; red_w[t] = sw;
    __syncthreads();
    for (int s = 256; s > 0; s >>= 1) {
        if (t < s) { red_a[t] += red_a[t + s]; red_w[t] += red_w[t + s]; }
        __syncthreads();
    }
    float mean_a = red_a[0] * (1.0f / NODES_PER_GRAPH);
    float mean_w = red_w[0] * (1.0f / NODES_PER_GRAPH);

    // v1/v2 and xs (coalesced W2 column reads)
    if (t < HID) {
        float a = 0.0f, c = 0.0f;
        for (int k = 0; k < HID; ++k) {
            float w2 = W2[k * HID + t];
            a += W1[k] * w2;
            c += b1[k] * w2;
        }
        xs[t] = mean_a * a + mean_w * c + b2[t];
    }
    __syncthreads();

    // input-gate preactivation for all 4H gates
    if (t < 4 * HID) {
        float acc = b_ih[t] + b_hh[t];
        const float4* wp = reinterpret_cast<const float4*>(W_ih + t * HID);
        #pragma unroll
        for (int q = 0; q < HID / 4; ++q) {
            float4 w4 = wp[q];
            acc += xs[4*q+0] * w4.x + xs[4*q+1] * w4.y + xs[4*q+2] * w4.z + xs[4*q+3] * w4.w;
        }
        Xg[(size_t)g * 4 * HID + t] = acc;
    }
}

// ---------------- rec: 5-step LSTM recurrence + head -----------------------
// thread t (<400) owns gate row t; W_hh row held in registers.
__global__ __launch_bounds__(512) void k_rec(const float* __restrict__ Xg,
                                             const float* __restrict__ W_hh,
                                             const float* __restrict__ W_out,
                                             const float* __restrict__ b_out,
                                             float* __restrict__ outp) {
    int b = blockIdx.x;            // 0..29
    int t = threadIdx.x;
    __shared__ float hs[HID], cs[HID];
    __shared__ float gsb[4 * HID];
    __shared__ float red[512];

    float wreg[HID];
    if (t < 4 * HID) {
        const float4* wp = reinterpret_cast<const float4*>(W_hh + t * HID);
        #pragma unroll
        for (int q = 0; q < HID / 4; ++q) {
            float4 w4 = wp[q];
            wreg[4*q+0] = w4.x; wreg[4*q+1] = w4.y; wreg[4*q+2] = w4.z; wreg[4*q+3] = w4.w;
        }
    }
    if (t < HID) { hs[t] = 0.0f; cs[t] = 0.0f; }
    __syncthreads();

    for (int step = 0; step < SEQ; ++step) {
        if (t < 4 * HID) {
            float acc = Xg[(size_t)(b * SEQ + step) * 4 * HID + t];
            #pragma unroll
            for (int k = 0; k < HID; ++k)
                acc += hs[k] * wreg[k];
            gsb[t] = acc;
        }
        __syncthreads();
        if (t < HID) {
            float ig = 1.0f / (1.0f + expf(-gsb[t]));
            float fg = 1.0f / (1.0f + expf(-gsb[HID + t]));
            float gg = tanhf(gsb[2 * HID + t]);
            float og = 1.0f / (1.0f + expf(-gsb[3 * HID + t]));
            float c  = fg * cs[t] + ig * gg;
            cs[t] = c;
            hs[t] = og * tanhf(c);
        }
        __syncthreads();
    }

    float v = (t < HID) ? hs[t] * W_out[t] : 0.0f;
    red[t] = v;
    __syncthreads();
    for (int s = 256; s > 0; s >>= 1) {
        if (t < s) red[t] += red[t + s];
        __syncthreads();
    }
    if (t == 0) outp[b] = red[0] + b_out[0];
}

// ---------------- launch ----------------
extern "C" void kernel_launch(void* const* d_in, const int* in_sizes, int n_in,
                              void* d_out, int out_size, void* d_ws, size_t ws_size,
                              hipStream_t stream) {
    const float* x    = (const float*)d_in[0];
    const int*   ei   = (const int*)d_in[1];
    const int*   srcp = ei;
    const int*   dstp = ei + N_EDGES;
    const float* W1   = (const float*)d_in[3];
    const float* b1   = (const float*)d_in[4];
    const float* W2   = (const float*)d_in[5];
    const float* b2   = (const float*)d_in[6];
    const float* W_ih = (const float*)d_in[7];
    const float* W_hh = (const float*)d_in[8];
    const float* b_ih = (const float*)d_in[9];
    const float* b_hh = (const float*)d_in[10];
    const float* W_out= (const float*)d_in[11];
    const float* b_out= (const float*)d_in[12];
    float* out = (float*)d_out;

    // workspace layout
    char* w = (char*)d_ws;
    int*  bucketCount = (int*)w;                         w += NB * sizeof(int);
    int*  bucketStart = (int*)w;                         w += (NB + 1) * sizeof(int);
    int*  blockBase   = (int*)w;                         w += (size_t)SBLK * NB * sizeof(int);
    unsigned int* sorted = (unsigned int*)w;             w += (size_t)N_EDGES * sizeof(unsigned int);
    float2* p   = (float2*)w;                            w += (size_t)N_NODES * sizeof(float2);
    float* agg1 = (float*)w;                             w += (size_t)N_NODES * sizeof(float);
    float* wsum = (float*)w;                             w += (size_t)N_NODES * sizeof(float);
    float* a1s  = (float*)w;                             w += (size_t)N_NODES * sizeof(float);
    float* agg2 = (float*)w;                             w += (size_t)N_NODES * sizeof(float);
    float* Xg   = (float*)w;                             w += (size_t)N_GRAPHS * 4 * HID * sizeof(float);

    k_zero<<<2, 256, 0, stream>>>(bucketCount, NB);
    k_s1  <<<SBLK, 256, 0, stream>>>(dstp, bucketCount, blockBase);
    k_scan<<<1, 256, 0, stream>>>(bucketCount, bucketStart);
    k_s2  <<<SBLK, 256, 0, stream>>>(srcp, dstp, bucketStart, blockBase, sorted);
    k_accA<<<NB, 256, 0, stream>>>(sorted, bucketStart, x, p);
    k_accB<<<NB, 256, 0, stream>>>(sorted, bucketStart, p, agg1, wsum, a1s);
    k_accC<<<NB, 256, 0, stream>>>(sorted, bucketStart, p, agg1, a1s, agg2);
    k_pre <<<N_GRAPHS, 512, 0, stream>>>(agg2, wsum, W1, b1, W2, b2, W_ih, b_ih, b_hh, Xg);
    k_rec <<<BATCH, 512, 0, stream>>>(Xg, W_hh, W_out, b_out, out);
}

// Round 6
// 95.896 us; speedup vs baseline: 3.8804x; 1.0396x over previous
//
#include <hip/hip_runtime.h>
#include <math.h>

#define N_NODES   150000
#define N_EDGES   1500000
#define N_GRAPHS  150
#define HID       100
#define BATCH     30
#define SEQ       5
#define NODES_PER_GRAPH 1000

#define NPB       256                        // nodes per bucket
#define NB        ((N_NODES + NPB - 1) / NPB)    // 586 buckets
#define SBLK      512                        // blocks for hist/scatter passes
#define EPB       2932                       // edges per sort block (mult of 4, 512*2932 >= E)

// ---------------- S1: per-block histogram (plain stores, no global atomics) --
__global__ __launch_bounds__(256) void k_s1(const int* __restrict__ dst,
                                            int* __restrict__ blockBase) {
    __shared__ int hist[NB];
    int t = threadIdx.x;
    for (int i = t; i < NB; i += 256) hist[i] = 0;
    __syncthreads();
    int base = blockIdx.x * EPB;
    int end  = min(base + EPB, N_EDGES);
    for (int i = base + t * 4; i < end; i += 1024) {
        int4 d = *reinterpret_cast<const int4*>(dst + i);
        atomicAdd(&hist[d.x >> 8], 1);
        atomicAdd(&hist[d.y >> 8], 1);
        atomicAdd(&hist[d.z >> 8], 1);
        atomicAdd(&hist[d.w >> 8], 1);
    }
    __syncthreads();
    for (int j = t; j < NB; j += 256)
        blockBase[blockIdx.x * NB + j] = hist[j];
}

// ---------------- colscan: per-bucket exclusive scan over the 512 blocks ----
__global__ __launch_bounds__(512) void k_colscan(int* __restrict__ blockBase,
                                                 int* __restrict__ bucketCount) {
    __shared__ int v[SBLK];
    int j = blockIdx.x;
    int t = threadIdx.x;
    int val = blockBase[t * NB + j];
    v[t] = val;
    __syncthreads();
    for (int off = 1; off < SBLK; off <<= 1) {
        int w = (t >= off) ? v[t - off] : 0;
        __syncthreads();
        v[t] += w;
        __syncthreads();
    }
    blockBase[t * NB + j] = v[t] - val;      // exclusive prefix for block t
    if (t == SBLK - 1) bucketCount[j] = v[t];
}

// ---------------- scan: exclusive prefix over bucketCount ------------------
__global__ __launch_bounds__(256) void k_scan(const int* __restrict__ cnt,
                                              int* __restrict__ start) {
    __shared__ int part[256];
    int t = threadIdx.x;
    int j0 = t * 3;
    int s = 0;
    #pragma unroll
    for (int k = 0; k < 3; ++k) { int j = j0 + k; if (j < NB) s += cnt[j]; }
    part[t] = s;
    __syncthreads();
    for (int off = 1; off < 256; off <<= 1) {
        int w = (t >= off) ? part[t - off] : 0;
        __syncthreads();
        part[t] += w;
        __syncthreads();
    }
    int run = part[t] - s;   // exclusive prefix of this thread's chunk
    #pragma unroll
    for (int k = 0; k < 3; ++k) {
        int j = j0 + k;
        if (j < NB) { start[j] = run; run += cnt[j]; }
    }
    if (t == 0) start[NB] = N_EDGES;
}

// ---------------- S2: scatter packed (src<<8 | dlocal) by bucket -----------
__global__ __launch_bounds__(256) void k_s2(const int* __restrict__ src,
                                            const int* __restrict__ dst,
                                            const int* __restrict__ bucketStart,
                                            const int* __restrict__ blockBase,
                                            unsigned int* __restrict__ sorted) {
    __shared__ int cursor[NB];
    __shared__ int baseS[NB];
    int t = threadIdx.x;
    const int* bb = blockBase + blockIdx.x * NB;
    for (int i = t; i < NB; i += 256) {
        cursor[i] = 0;
        baseS[i] = bucketStart[i] + bb[i];
    }
    __syncthreads();
    int base = blockIdx.x * EPB;
    int end  = min(base + EPB, N_EDGES);
    for (int i = base + t * 4; i < end; i += 1024) {
        int4 s4 = *reinterpret_cast<const int4*>(src + i);
        int4 d4 = *reinterpret_cast<const int4*>(dst + i);
        int bs[4] = { d4.x >> 8, d4.y >> 8, d4.z >> 8, d4.w >> 8 };
        int sv[4] = { s4.x, s4.y, s4.z, s4.w };
        int dl[4] = { d4.x & 255, d4.y & 255, d4.z & 255, d4.w & 255 };
        #pragma unroll
        for (int k = 0; k < 4; ++k) {
            int b = bs[k];
            int idx = atomicAdd(&cursor[b], 1);
            sorted[baseS[b] + idx] = ((unsigned int)sv[k] << 8) | (unsigned int)dl[k];
        }
    }
}

// ---------------- accumA: degree -> dinv, p = (dinv, dinv*x) ---------------
__global__ __launch_bounds__(256) void k_accA(const unsigned int* __restrict__ sorted,
                                              const int* __restrict__ bucketStart,
                                              const float* __restrict__ x,
                                              float2* __restrict__ p) {
    __shared__ int degI[2][NPB];
    int b = blockIdx.x;
    int t = threadIdx.x;
    int n0 = b << 8;
    int nn = min(NPB, N_NODES - n0);
    degI[0][t] = 0; degI[1][t] = 0;
    __syncthreads();
    int e0 = bucketStart[b], e1 = bucketStart[b + 1];
    int rep = t & 1;
    int e0a = min((e0 + 3) & ~3, e1);
    if (e0 + t < e0a) atomicAdd(&degI[rep][sorted[e0 + t] & 255], 1);
    int nvec = (e1 - e0a) >> 2;
    for (int v = t; v < nvec; v += 256) {
        uint4 u4 = *reinterpret_cast<const uint4*>(sorted + e0a + v * 4);
        atomicAdd(&degI[rep][u4.x & 255], 1);
        atomicAdd(&degI[rep][u4.y & 255], 1);
        atomicAdd(&degI[rep][u4.z & 255], 1);
        atomicAdd(&degI[rep][u4.w & 255], 1);
    }
    int tail0 = e0a + (nvec << 2);
    if (tail0 + t < e1) atomicAdd(&degI[rep][sorted[tail0 + t] & 255], 1);
    __syncthreads();
    if (t < nn) {
        float dv = 1.0f / sqrtf((float)(1 + degI[0][t] + degI[1][t]));
        p[n0 + t] = make_float2(dv, dv * x[n0 + t]);
    }
}

// ---------------- accumB: t1,t2 -> agg1, wsum, a1s -------------------------
__global__ __launch_bounds__(256) void k_accB(const unsigned int* __restrict__ sorted,
                                              const int* __restrict__ bucketStart,
                                              const float2* __restrict__ p,
                                              float* __restrict__ agg1,
                                              float* __restrict__ wsum,
                                              float* __restrict__ a1s) {
    __shared__ float t1[2][NPB], t2[2][NPB];
    int b = blockIdx.x;
    int t = threadIdx.x;
    int n0 = b << 8;
    int nn = min(NPB, N_NODES - n0);
    t1[0][t] = 0.0f; t1[1][t] = 0.0f; t2[0][t] = 0.0f; t2[1][t] = 0.0f;
    __syncthreads();
    int e0 = bucketStart[b], e1 = bucketStart[b + 1];
    int rep = t & 1;
    int e0a = min((e0 + 3) & ~3, e1);
    if (e0 + t < e0a) {
        unsigned int u = sorted[e0 + t];
        float2 pv = p[u >> 8];
        atomicAdd(&t2[rep][u & 255], pv.x);
        atomicAdd(&t1[rep][u & 255], pv.y);
    }
    int nvec = (e1 - e0a) >> 2;
    for (int v = t; v < nvec; v += 256) {
        uint4 u4 = *reinterpret_cast<const uint4*>(sorted + e0a + v * 4);
        float2 p0 = p[u4.x >> 8];
        float2 p1 = p[u4.y >> 8];
        float2 p2 = p[u4.z >> 8];
        float2 p3 = p[u4.w >> 8];
        atomicAdd(&t2[rep][u4.x & 255], p0.x);
        atomicAdd(&t1[rep][u4.x & 255], p0.y);
        atomicAdd(&t2[rep][u4.y & 255], p1.x);
        atomicAdd(&t1[rep][u4.y & 255], p1.y);
        atomicAdd(&t2[rep][u4.z & 255], p2.x);
        atomicAdd(&t1[rep][u4.z & 255], p2.y);
        atomicAdd(&t2[rep][u4.w & 255], p3.x);
        atomicAdd(&t1[rep][u4.w & 255], p3.y);
    }
    int tail0 = e0a + (nvec << 2);
    if (tail0 + t < e1) {
        unsigned int u = sorted[tail0 + t];
        float2 pv = p[u >> 8];
        atomicAdd(&t2[rep][u & 255], pv.x);
        atomicAdd(&t1[rep][u & 255], pv.y);
    }
    __syncthreads();
    if (t < nn) {
        float2 pv = p[n0 + t];
        float dv = pv.x;
        float T1 = t1[0][t] + t1[1][t];
        float T2 = t2[0][t] + t2[1][t];
        float a = dv * T1 + dv * pv.y;   // dinv*(t1 + dinv*x)
        agg1[n0 + t] = a;
        wsum[n0 + t] = dv * (T2 + dv);
        a1s[n0 + t]  = dv * a;
    }
}

// ---------------- accumC: u -> agg2 ----------------------------------------
__global__ __launch_bounds__(256) void k_accC(const unsigned int* __restrict__ sorted,
                                              const int* __restrict__ bucketStart,
                                              const float2* __restrict__ p,
                                              const float* __restrict__ agg1,
                                              const float* __restrict__ a1s,
                                              float* __restrict__ agg2) {
    __shared__ float ua[2][NPB];
    int b = blockIdx.x;
    int t = threadIdx.x;
    int n0 = b << 8;
    int nn = min(NPB, N_NODES - n0);
    ua[0][t] = 0.0f; ua[1][t] = 0.0f;
    __syncthreads();
    int e0 = bucketStart[b], e1 = bucketStart[b + 1];
    int rep = t & 1;
    int e0a = min((e0 + 3) & ~3, e1);
    if (e0 + t < e0a) {
        unsigned int u = sorted[e0 + t];
        atomicAdd(&ua[rep][u & 255], a1s[u >> 8]);
    }
    int nvec = (e1 - e0a) >> 2;
    for (int v = t; v < nvec; v += 256) {
        uint4 u4 = *reinterpret_cast<const uint4*>(sorted + e0a + v * 4);
        atomicAdd(&ua[rep][u4.x & 255], a1s[u4.x >> 8]);
        atomicAdd(&ua[rep][u4.y & 255], a1s[u4.y >> 8]);
        atomicAdd(&ua[rep][u4.z & 255], a1s[u4.z >> 8]);
        atomicAdd(&ua[rep][u4.w & 255], a1s[u4.w >> 8]);
    }
    int tail0 = e0a + (nvec << 2);
    if (tail0 + t < e1) {
        unsigned int u = sorted[tail0 + t];
        atomicAdd(&ua[rep][u & 255], a1s[u >> 8]);
    }
    __syncthreads();
    if (t < nn) {
        float dv = p[n0 + t].x;
        agg2[n0 + t] = dv * (ua[0][t] + ua[1][t] + dv * agg1[n0 + t]);
    }
}

// ---------------- pre: per-graph means -> xs -> Xg (input gates) -----------
__global__ __launch_bounds__(512) void k_pre(const float* __restrict__ agg2,
                                             const float* __restrict__ wsum,
                                             const float* __restrict__ W1,
                                             const float* __restrict__ b1,
                                             const float* __restrict__ W2,
                                             const float* __restrict__ b2,
                                             const float* __restrict__ W_ih,
                                             const float* __restrict__ b_ih,
                                             const float* __restrict__ b_hh,
                                             float* __restrict__ Xg) {
    int g = blockIdx.x;            // 0..149
    int t = threadIdx.x;
    __shared__ float xs[HID];
    __shared__ float red_a[512], red_w[512];

    const float* pa = agg2 + (size_t)g * NODES_PER_GRAPH;
    const float* pw = wsum + (size_t)g * NODES_PER_GRAPH;
    float sa = 0.0f, sw = 0.0f;
    for (int n = t; n < NODES_PER_GRAPH; n += 512) { sa += pa[n]; sw += pw[n]; }
    red_a[t] = sa; red_w[t] = sw;
    __syncthreads();
    for (int s = 256; s > 0; s >>= 1) {
        if (t < s) { red_a[t] += red_a[t + s]; red_w[t] += red_w[t + s]; }
        __syncthreads();
    }
    float mean_a = red_a[0] * (1.0f / NODES_PER_GRAPH);
    float mean_w = red_w[0] * (1.0f / NODES_PER_GRAPH);

    if (t < HID) {
        float a = 0.0f, c = 0.0f;
        for (int k = 0; k < HID; ++k) {
            float w2 = W2[k * HID + t];
            a += W1[k] * w2;
            c += b1[k] * w2;
        }
        xs[t] = mean_a * a + mean_w * c + b2[t];
    }
    __syncthreads();

    if (t < 4 * HID) {
        float acc = b_ih[t] + b_hh[t];
        const float4* wp = reinterpret_cast<const float4*>(W_ih + t * HID);
        #pragma unroll
        for (int q = 0; q < HID / 4; ++q) {
            float4 w4 = wp[q];
            acc += xs[4*q+0] * w4.x + xs[4*q+1] * w4.y + xs[4*q+2] * w4.z + xs[4*q+3] * w4.w;
        }
        Xg[(size_t)g * 4 * HID + t] = acc;
    }
}

// ---------------- rec: 5-step LSTM recurrence + head -----------------------
__global__ __launch_bounds__(512) void k_rec(const float* __restrict__ Xg,
                                             const float* __restrict__ W_hh,
                                             const float* __restrict__ W_out,
                                             const float* __restrict__ b_out,
                                             float* __restrict__ outp) {
    int b = blockIdx.x;            // 0..29
    int t = threadIdx.x;
    __shared__ float hs[HID], cs[HID];
    __shared__ float gsb[4 * HID];
    __shared__ float red[512];

    float wreg[HID];
    if (t < 4 * HID) {
        const float4* wp = reinterpret_cast<const float4*>(W_hh + t * HID);
        #pragma unroll
        for (int q = 0; q < HID / 4; ++q) {
            float4 w4 = wp[q];
            wreg[4*q+0] = w4.x; wreg[4*q+1] = w4.y; wreg[4*q+2] = w4.z; wreg[4*q+3] = w4.w;
        }
    }
    if (t < HID) { hs[t] = 0.0f; cs[t] = 0.0f; }
    __syncthreads();

    for (int step = 0; step < SEQ; ++step) {
        if (t < 4 * HID) {
            float acc = Xg[(size_t)(b * SEQ + step) * 4 * HID + t];
            #pragma unroll
            for (int k = 0; k < HID; ++k)
                acc += hs[k] * wreg[k];
            gsb[t] = acc;
        }
        __syncthreads();
        if (t < HID) {
            float ig = 1.0f / (1.0f + expf(-gsb[t]));
            float fg = 1.0f / (1.0f + expf(-gsb[HID + t]));
            float gg = tanhf(gsb[2 * HID + t]);
            float og = 1.0f / (1.0f + expf(-gsb[3 * HID + t]));
            float c  = fg * cs[t] + ig * gg;
            cs[t] = c;
            hs[t] = og * tanhf(c);
        }
        __syncthreads();
    }

    float v = (t < HID) ? hs[t] * W_out[t] : 0.0f;
    red[t] = v;
    __syncthreads();
    for (int s = 256; s > 0; s >>= 1) {
        if (t < s) red[t] += red[t + s];
        __syncthreads();
    }
    if (t == 0) outp[b] = red[0] + b_out[0];
}

// ---------------- launch ----------------
static inline char* align_up(char* p, size_t a) {
    return (char*)(((uintptr_t)p + (a - 1)) & ~(uintptr_t)(a - 1));
}

extern "C" void kernel_launch(void* const* d_in, const int* in_sizes, int n_in,
                              void* d_out, int out_size, void* d_ws, size_t ws_size,
                              hipStream_t stream) {
    const float* x    = (const float*)d_in[0];
    const int*   ei   = (const int*)d_in[1];
    const int*   srcp = ei;
    const int*   dstp = ei + N_EDGES;
    const float* W1   = (const float*)d_in[3];
    const float* b1   = (const float*)d_in[4];
    const float* W2   = (const float*)d_in[5];
    const float* b2   = (const float*)d_in[6];
    const float* W_ih = (const float*)d_in[7];
    const float* W_hh = (const float*)d_in[8];
    const float* b_ih = (const float*)d_in[9];
    const float* b_hh = (const float*)d_in[10];
    const float* W_out= (const float*)d_in[11];
    const float* b_out= (const float*)d_in[12];
    float* out = (float*)d_out;

    // workspace layout (each region 64B-aligned; uint4 loads need 16B)
    char* w = (char*)d_ws;
    int*  bucketCount = (int*)w;            w = align_up(w + NB * sizeof(int), 64);
    int*  bucketStart = (int*)w;            w = align_up(w + (NB + 1) * sizeof(int), 64);
    int*  blockBase   = (int*)w;            w = align_up(w + (size_t)SBLK * NB * sizeof(int), 64);
    unsigned int* sorted = (unsigned int*)w; w = align_up(w + (size_t)N_EDGES * sizeof(unsigned int), 64);
    float2* p   = (float2*)w;               w = align_up(w + (size_t)N_NODES * sizeof(float2), 64);
    float* agg1 = (float*)w;                w = align_up(w + (size_t)N_NODES * sizeof(float), 64);
    float* wsum = (float*)w;                w = align_up(w + (size_t)N_NODES * sizeof(float), 64);
    float* a1s  = (float*)w;                w = align_up(w + (size_t)N_NODES * sizeof(float), 64);
    float* agg2 = (float*)w;                w = align_up(w + (size_t)N_NODES * sizeof(float), 64);
    float* Xg   = (float*)w;                w = align_up(w + (size_t)N_GRAPHS * 4 * HID * sizeof(float), 64);

    k_s1     <<<SBLK, 256, 0, stream>>>(dstp, blockBase);
    k_colscan<<<NB, SBLK, 0, stream>>>(blockBase, bucketCount);
    k_scan   <<<1, 256, 0, stream>>>(bucketCount, bucketStart);
    k_s2     <<<SBLK, 256, 0, stream>>>(srcp, dstp, bucketStart, blockBase, sorted);
    k_accA   <<<NB, 256, 0, stream>>>(sorted, bucketStart, x, p);
    k_accB   <<<NB, 256, 0, stream>>>(sorted, bucketStart, p, agg1, wsum, a1s);
    k_accC   <<<NB, 256, 0, stream>>>(sorted, bucketStart, p, agg1, a1s, agg2);
    k_pre    <<<N_GRAPHS, 512, 0, stream>>>(agg2, wsum, W1, b1, W2, b2, W_ih, b_ih, b_hh, Xg);
    k_rec    <<<BATCH, 512, 0, stream>>>(Xg, W_hh, W_out, b_out, out);
}

// Round 7
// 86.392 us; speedup vs baseline: 4.3073x; 1.1100x over previous
//
#include <hip/hip_runtime.h>
#include <math.h>

#define N_NODES   150000
#define N_EDGES   1500000
#define N_GRAPHS  150
#define HID       100
#define BATCH     30
#define SEQ       5
#define NODES_PER_GRAPH 1000

#define NPB       256                        // nodes per bucket
#define NB        ((N_NODES + NPB - 1) / NPB)    // 586 buckets
#define SBLK      512                        // blocks for hist/scatter passes
#define EPB       2932                       // edges per sort block (mult of 4, 512*2932 >= E)

// ---------------- S1: per-block histogram (plain stores, no global atomics) --
__global__ __launch_bounds__(256) void k_s1(const int* __restrict__ dst,
                                            int* __restrict__ blockBase) {
    __shared__ int hist[NB];
    int t = threadIdx.x;
    for (int i = t; i < NB; i += 256) hist[i] = 0;
    __syncthreads();
    int base = blockIdx.x * EPB;
    int end  = min(base + EPB, N_EDGES);
    for (int i = base + t * 4; i < end; i += 1024) {
        int4 d = *reinterpret_cast<const int4*>(dst + i);
        atomicAdd(&hist[d.x >> 8], 1);
        atomicAdd(&hist[d.y >> 8], 1);
        atomicAdd(&hist[d.z >> 8], 1);
        atomicAdd(&hist[d.w >> 8], 1);
    }
    __syncthreads();
    for (int j = t; j < NB; j += 256)
        blockBase[blockIdx.x * NB + j] = hist[j];
}

// ---------------- colscan: per-bucket exclusive scan over the 512 blocks ----
__global__ __launch_bounds__(512) void k_colscan(int* __restrict__ blockBase,
                                                 int* __restrict__ bucketCount) {
    __shared__ int v[SBLK];
    int j = blockIdx.x;
    int t = threadIdx.x;
    int val = blockBase[t * NB + j];
    v[t] = val;
    __syncthreads();
    for (int off = 1; off < SBLK; off <<= 1) {
        int w = (t >= off) ? v[t - off] : 0;
        __syncthreads();
        v[t] += w;
        __syncthreads();
    }
    blockBase[t * NB + j] = v[t] - val;      // exclusive prefix for block t
    if (t == SBLK - 1) bucketCount[j] = v[t];
}

// ---------------- scan: exclusive prefix over bucketCount (+zero graph sums)
__global__ __launch_bounds__(256) void k_scan(const int* __restrict__ cnt,
                                              int* __restrict__ start,
                                              float* __restrict__ graphA,
                                              float* __restrict__ graphW) {
    __shared__ int part[256];
    int t = threadIdx.x;
    if (t < N_GRAPHS) { graphA[t] = 0.0f; graphW[t] = 0.0f; }
    int j0 = t * 3;
    int s = 0;
    #pragma unroll
    for (int k = 0; k < 3; ++k) { int j = j0 + k; if (j < NB) s += cnt[j]; }
    part[t] = s;
    __syncthreads();
    for (int off = 1; off < 256; off <<= 1) {
        int w = (t >= off) ? part[t - off] : 0;
        __syncthreads();
        part[t] += w;
        __syncthreads();
    }
    int run = part[t] - s;   // exclusive prefix of this thread's chunk
    #pragma unroll
    for (int k = 0; k < 3; ++k) {
        int j = j0 + k;
        if (j < NB) { start[j] = run; run += cnt[j]; }
    }
    if (t == 0) start[NB] = N_EDGES;
}

// ---------------- S2: scatter packed (src<<8 | dlocal) by bucket -----------
__global__ __launch_bounds__(256) void k_s2(const int* __restrict__ src,
                                            const int* __restrict__ dst,
                                            const int* __restrict__ bucketStart,
                                            const int* __restrict__ blockBase,
                                            unsigned int* __restrict__ sorted) {
    __shared__ int cursor[NB];
    __shared__ int baseS[NB];
    int t = threadIdx.x;
    const int* bb = blockBase + blockIdx.x * NB;
    for (int i = t; i < NB; i += 256) {
        cursor[i] = 0;
        baseS[i] = bucketStart[i] + bb[i];
    }
    __syncthreads();
    int base = blockIdx.x * EPB;
    int end  = min(base + EPB, N_EDGES);
    for (int i = base + t * 4; i < end; i += 1024) {
        int4 s4 = *reinterpret_cast<const int4*>(src + i);
        int4 d4 = *reinterpret_cast<const int4*>(dst + i);
        int bs[4] = { d4.x >> 8, d4.y >> 8, d4.z >> 8, d4.w >> 8 };
        int sv[4] = { s4.x, s4.y, s4.z, s4.w };
        int dl[4] = { d4.x & 255, d4.y & 255, d4.z & 255, d4.w & 255 };
        #pragma unroll
        for (int k = 0; k < 4; ++k) {
            int b = bs[k];
            int idx = atomicAdd(&cursor[b], 1);
            sorted[baseS[b] + idx] = ((unsigned int)sv[k] << 8) | (unsigned int)dl[k];
        }
    }
}

// 2-bin (graph-boundary) block reduction helper: reduces `val` over 256
// threads into graph g0 (t < thresh) and g0+1 (t >= thresh).
__device__ __forceinline__ void graph_reduce_add(float val, int thresh, int nn,
                                                 int g0, float* red, int t,
                                                 float* __restrict__ gdst) {
    red[t] = (t < thresh) ? val : 0.0f;
    __syncthreads();
    for (int s = 128; s > 0; s >>= 1) {
        if (t < s) red[t] += red[t + s];
        __syncthreads();
    }
    if (t == 0) atomicAdd(&gdst[g0], red[0]);
    __syncthreads();
    red[t] = (t >= thresh) ? val : 0.0f;
    __syncthreads();
    for (int s = 128; s > 0; s >>= 1) {
        if (t < s) red[t] += red[t + s];
        __syncthreads();
    }
    if (t == 0 && thresh < nn) atomicAdd(&gdst[g0 + 1], red[0]);
}

// ---------------- accumA: degree -> pd=dinv, px=dinv*x; graphW += dv^2 -----
__global__ __launch_bounds__(256) void k_accA(const unsigned int* __restrict__ sorted,
                                              const int* __restrict__ bucketStart,
                                              const float* __restrict__ x,
                                              float* __restrict__ pd,
                                              float* __restrict__ px,
                                              float* __restrict__ graphW) {
    __shared__ int degI[2][NPB];
    __shared__ float red[256];
    int b = blockIdx.x;
    int t = threadIdx.x;
    int n0 = b << 8;
    int nn = min(NPB, N_NODES - n0);
    degI[0][t] = 0; degI[1][t] = 0;
    __syncthreads();
    int e0 = bucketStart[b], e1 = bucketStart[b + 1];
    int rep = t & 1;
    int e0a = min((e0 + 3) & ~3, e1);
    if (e0 + t < e0a) atomicAdd(&degI[rep][sorted[e0 + t] & 255], 1);
    int nvec = (e1 - e0a) >> 2;
    for (int v = t; v < nvec; v += 256) {
        uint4 u4 = *reinterpret_cast<const uint4*>(sorted + e0a + v * 4);
        atomicAdd(&degI[rep][u4.x & 255], 1);
        atomicAdd(&degI[rep][u4.y & 255], 1);
        atomicAdd(&degI[rep][u4.z & 255], 1);
        atomicAdd(&degI[rep][u4.w & 255], 1);
    }
    int tail0 = e0a + (nvec << 2);
    if (tail0 + t < e1) atomicAdd(&degI[rep][sorted[tail0 + t] & 255], 1);
    __syncthreads();
    float val = 0.0f;
    if (t < nn) {
        float dv = 1.0f / sqrtf((float)(1 + degI[0][t] + degI[1][t]));
        pd[n0 + t] = dv;
        px[n0 + t] = dv * x[n0 + t];
        val = dv * dv;
    }
    int g0 = n0 / 1000;
    int thresh = (g0 + 1) * 1000 - n0;
    graph_reduce_add(val, thresh, nn, g0, red, t, graphW);
}

// ---------------- accumB: t1 -> pa2=(dinv, a1s); graphA += dv^2*agg1 -------
__global__ __launch_bounds__(256) void k_accB(const unsigned int* __restrict__ sorted,
                                              const int* __restrict__ bucketStart,
                                              const float* __restrict__ pd,
                                              const float* __restrict__ px,
                                              float2* __restrict__ pa2,
                                              float* __restrict__ graphA) {
    __shared__ float t1[2][NPB];
    __shared__ float red[256];
    int b = blockIdx.x;
    int t = threadIdx.x;
    int n0 = b << 8;
    int nn = min(NPB, N_NODES - n0);
    t1[0][t] = 0.0f; t1[1][t] = 0.0f;
    __syncthreads();
    int e0 = bucketStart[b], e1 = bucketStart[b + 1];
    int rep = t & 1;
    int e0a = min((e0 + 3) & ~3, e1);
    if (e0 + t < e0a) {
        unsigned int u = sorted[e0 + t];
        atomicAdd(&t1[rep][u & 255], px[u >> 8]);
    }
    int nvec = (e1 - e0a) >> 2;
    for (int v = t; v < nvec; v += 256) {
        uint4 u4 = *reinterpret_cast<const uint4*>(sorted + e0a + v * 4);
        float p0 = px[u4.x >> 8];
        float p1 = px[u4.y >> 8];
        float p2 = px[u4.z >> 8];
        float p3 = px[u4.w >> 8];
        atomicAdd(&t1[rep][u4.x & 255], p0);
        atomicAdd(&t1[rep][u4.y & 255], p1);
        atomicAdd(&t1[rep][u4.z & 255], p2);
        atomicAdd(&t1[rep][u4.w & 255], p3);
    }
    int tail0 = e0a + (nvec << 2);
    if (tail0 + t < e1) {
        unsigned int u = sorted[tail0 + t];
        atomicAdd(&t1[rep][u & 255], px[u >> 8]);
    }
    __syncthreads();
    float val = 0.0f;
    if (t < nn) {
        float dv = pd[n0 + t];
        float T1 = t1[0][t] + t1[1][t];
        float agg1 = dv * T1 + dv * px[n0 + t];   // dinv*(t1 + dinv*x)
        float a1 = dv * agg1;
        pa2[n0 + t] = make_float2(dv, a1);
        val = dv * a1;                             // dv^2 * agg1 (self term)
    }
    int g0 = n0 / 1000;
    int thresh = (g0 + 1) * 1000 - n0;
    graph_reduce_add(val, thresh, nn, g0, red, t, graphA);
}

// ---------------- accumG: edge terms -> graphA, graphW ---------------------
// graphA[g(dst)] += dinv[dst]*a1s[src];  graphW[g(dst)] += dinv[dst]*dinv[src]
__global__ __launch_bounds__(256) void k_accG(const unsigned int* __restrict__ sorted,
                                              const int* __restrict__ bucketStart,
                                              const float* __restrict__ pd,
                                              const float2* __restrict__ pa2,
                                              float* __restrict__ graphA,
                                              float* __restrict__ graphW) {
    __shared__ float dvl[NPB];
    __shared__ float4 red4[256];
    int b = blockIdx.x;
    int t = threadIdx.x;
    int n0 = b << 8;
    int nn = min(NPB, N_NODES - n0);
    dvl[t] = (t < nn) ? pd[n0 + t] : 0.0f;
    __syncthreads();
    int g0 = n0 / 1000;
    int thresh = (g0 + 1) * 1000 - n0;
    float sa0 = 0.f, sa1 = 0.f, sw0 = 0.f, sw1 = 0.f;
    int e0 = bucketStart[b], e1 = bucketStart[b + 1];
    int e0a = min((e0 + 3) & ~3, e1);
    auto proc = [&](unsigned int u) {
        int dl = (int)(u & 255);
        float dvd = dvl[dl];
        float2 v = pa2[u >> 8];
        if (dl < thresh) { sw0 += dvd * v.x; sa0 += dvd * v.y; }
        else             { sw1 += dvd * v.x; sa1 += dvd * v.y; }
    };
    if (e0 + t < e0a) proc(sorted[e0 + t]);
    int nvec = (e1 - e0a) >> 2;
    for (int v = t; v < nvec; v += 256) {
        uint4 u4 = *reinterpret_cast<const uint4*>(sorted + e0a + v * 4);
        proc(u4.x); proc(u4.y); proc(u4.z); proc(u4.w);
    }
    int tail0 = e0a + (nvec << 2);
    if (tail0 + t < e1) proc(sorted[tail0 + t]);
    red4[t] = make_float4(sa0, sa1, sw0, sw1);
    __syncthreads();
    for (int s = 128; s > 0; s >>= 1) {
        if (t < s) {
            red4[t].x += red4[t + s].x; red4[t].y += red4[t + s].y;
            red4[t].z += red4[t + s].z; red4[t].w += red4[t + s].w;
        }
        __syncthreads();
    }
    if (t == 0) {
        atomicAdd(&graphA[g0], red4[0].x);
        atomicAdd(&graphW[g0], red4[0].z);
        if (thresh < nn) {
            atomicAdd(&graphA[g0 + 1], red4[0].y);
            atomicAdd(&graphW[g0 + 1], red4[0].w);
        }
    }
}

// ---------------- tail: xs -> gates (W_ih) -> LSTM (W_hh) -> head ----------
__global__ __launch_bounds__(512) void k_tail(const float* __restrict__ graphA,
                                              const float* __restrict__ graphW,
                                              const float* __restrict__ W1,
                                              const float* __restrict__ b1,
                                              const float* __restrict__ W2,
                                              const float* __restrict__ b2,
                                              const float* __restrict__ W_ih,
                                              const float* __restrict__ W_hh,
                                              const float* __restrict__ b_ih,
                                              const float* __restrict__ b_hh,
                                              const float* __restrict__ W_out,
                                              const float* __restrict__ b_out,
                                              float* __restrict__ outp) {
    int b = blockIdx.x;            // 0..29
    int t = threadIdx.x;
    __shared__ float v1[HID], v2[HID];
    __shared__ float xs_l[SEQ][HID];
    __shared__ float Xg_l[SEQ][4 * HID];
    __shared__ float hs[HID], cs[HID], gsb[4 * HID];
    __shared__ float red[512];

    // v1 = W1^T W2, v2 = b1^T W2 (coalesced column reads)
    if (t < HID) {
        float a = 0.0f, c = 0.0f;
        for (int k = 0; k < HID; ++k) {
            float w2 = W2[k * HID + t];
            a += W1[k] * w2;
            c += b1[k] * w2;
        }
        v1[t] = a; v2[t] = c;
    }
    __syncthreads();

    // pooled inputs for the 5 timesteps of this batch element
    if (t < SEQ * HID) {
        int s = t / HID, j = t - s * HID;
        int g = b * SEQ + s;
        float ma = graphA[g] * (1.0f / NODES_PER_GRAPH);
        float mw = graphW[g] * (1.0f / NODES_PER_GRAPH);
        xs_l[s][j] = ma * v1[j] + mw * v2[j] + b2[j];
    }
    __syncthreads();

    float wreg[HID];
    if (t < 4 * HID) {
        // input-gate GEMM: W_ih row in registers, all 5 steps
        const float4* wp = reinterpret_cast<const float4*>(W_ih + t * HID);
        #pragma unroll
        for (int q = 0; q < HID / 4; ++q) {
            float4 w4 = wp[q];
            wreg[4*q+0] = w4.x; wreg[4*q+1] = w4.y; wreg[4*q+2] = w4.z; wreg[4*q+3] = w4.w;
        }
        float bias = b_ih[t] + b_hh[t];
        for (int s = 0; s < SEQ; ++s) {
            float acc = bias;
            #pragma unroll
            for (int k = 0; k < HID; ++k)
                acc += xs_l[s][k] * wreg[k];
            Xg_l[s][t] = acc;
        }
        // reload registers with W_hh row for the recurrence
        wp = reinterpret_cast<const float4*>(W_hh + t * HID);
        #pragma unroll
        for (int q = 0; q < HID / 4; ++q) {
            float4 w4 = wp[q];
            wreg[4*q+0] = w4.x; wreg[4*q+1] = w4.y; wreg[4*q+2] = w4.z; wreg[4*q+3] = w4.w;
        }
    }
    if (t < HID) { hs[t] = 0.0f; cs[t] = 0.0f; }
    __syncthreads();

    for (int step = 0; step < SEQ; ++step) {
        if (t < 4 * HID) {
            float acc = Xg_l[step][t];
            #pragma unroll
            for (int k = 0; k < HID; ++k)
                acc += hs[k] * wreg[k];
            gsb[t] = acc;
        }
        __syncthreads();
        if (t < HID) {
            float ig = 1.0f / (1.0f + expf(-gsb[t]));
            float fg = 1.0f / (1.0f + expf(-gsb[HID + t]));
            float gg = tanhf(gsb[2 * HID + t]);
            float og = 1.0f / (1.0f + expf(-gsb[3 * HID + t]));
            float c  = fg * cs[t] + ig * gg;
            cs[t] = c;
            hs[t] = og * tanhf(c);
        }
        __syncthreads();
    }

    float v = (t < HID) ? hs[t] * W_out[t] : 0.0f;
    red[t] = v;
    __syncthreads();
    for (int s = 256; s > 0; s >>= 1) {
        if (t < s) red[t] += red[t + s];
        __syncthreads();
    }
    if (t == 0) outp[b] = red[0] + b_out[0];
}

// ---------------- launch ----------------
static inline char* align_up(char* p, size_t a) {
    return (char*)(((uintptr_t)p + (a - 1)) & ~(uintptr_t)(a - 1));
}

extern "C" void kernel_launch(void* const* d_in, const int* in_sizes, int n_in,
                              void* d_out, int out_size, void* d_ws, size_t ws_size,
                              hipStream_t stream) {
    const float* x    = (const float*)d_in[0];
    const int*   ei   = (const int*)d_in[1];
    const int*   srcp = ei;
    const int*   dstp = ei + N_EDGES;
    const float* W1   = (const float*)d_in[3];
    const float* b1   = (const float*)d_in[4];
    const float* W2   = (const float*)d_in[5];
    const float* b2   = (const float*)d_in[6];
    const float* W_ih = (const float*)d_in[7];
    const float* W_hh = (const float*)d_in[8];
    const float* b_ih = (const float*)d_in[9];
    const float* b_hh = (const float*)d_in[10];
    const float* W_out= (const float*)d_in[11];
    const float* b_out= (const float*)d_in[12];
    float* out = (float*)d_out;

    // workspace layout (each region 64B-aligned; uint4 loads need 16B)
    char* w = (char*)d_ws;
    int*  bucketCount = (int*)w;             w = align_up(w + NB * sizeof(int), 64);
    int*  bucketStart = (int*)w;             w = align_up(w + (NB + 1) * sizeof(int), 64);
    int*  blockBase   = (int*)w;             w = align_up(w + (size_t)SBLK * NB * sizeof(int), 64);
    unsigned int* sorted = (unsigned int*)w; w = align_up(w + (size_t)N_EDGES * sizeof(unsigned int), 64);
    float*  pd   = (float*)w;                w = align_up(w + (size_t)N_NODES * sizeof(float), 64);
    float*  px   = (float*)w;                w = align_up(w + (size_t)N_NODES * sizeof(float), 64);
    float2* pa2  = (float2*)w;               w = align_up(w + (size_t)N_NODES * sizeof(float2), 64);
    float* graphA = (float*)w;               w = align_up(w + N_GRAPHS * sizeof(float), 64);
    float* graphW = (float*)w;               w = align_up(w + N_GRAPHS * sizeof(float), 64);

    k_s1     <<<SBLK, 256, 0, stream>>>(dstp, blockBase);
    k_colscan<<<NB, SBLK, 0, stream>>>(blockBase, bucketCount);
    k_scan   <<<1, 256, 0, stream>>>(bucketCount, bucketStart, graphA, graphW);
    k_s2     <<<SBLK, 256, 0, stream>>>(srcp, dstp, bucketStart, blockBase, sorted);
    k_accA   <<<NB, 256, 0, stream>>>(sorted, bucketStart, x, pd, px, graphW);
    k_accB   <<<NB, 256, 0, stream>>>(sorted, bucketStart, pd, px, pa2, graphA);
    k_accG   <<<NB, 256, 0, stream>>>(sorted, bucketStart, pd, pa2, graphA, graphW);
    k_tail   <<<BATCH, 512, 0, stream>>>(graphA, graphW, W1, b1, W2, b2,
                                         W_ih, W_hh, b_ih, b_hh, W_out, b_out, out);
}